// Round 2
// baseline (602.717 us; speedup 1.0000x reference)
//
#include <hip/hip_runtime.h>
#include <cstdint>
#include <cstddef>

// Problem shape (fixed): B=4, Sq=2048 -> S=8192 tokens, M=1024, E=8, H=4096,
// C=S/E=1024 capacity.
// WS BUDGET: keep total workspace under ~84 MB. Round-1 failure was an OOB
// overrun of d_ws (218 MB footprint) corrupting the harness's pristine input
// copies -> consistent post-timing divergence. H is processed in 2 halves of
// 2048 with a ping-ponged 32 MB weight buffer to stay small.
#define S_TOK 8192
#define MDIM  1024
#define EEXP  8
#define HDIM  4096
#define HHALF 2048
#define CAP   1024

typedef __attribute__((ext_vector_type(8))) short short8v;   // 8 bf16 in 4 VGPRs
typedef __attribute__((ext_vector_type(4))) float f32x4;

__device__ __forceinline__ short f2bf(float f) {
    __bf16 b = (__bf16)f;                 // RNE hardware convert on gfx950
    return __builtin_bit_cast(short, b);
}

__device__ __forceinline__ void gld_lds16(const void* g, void* l) {
    __builtin_amdgcn_global_load_lds(
        (const __attribute__((address_space(1))) void*)g,
        (__attribute__((address_space(3))) void*)l, 16, 0, 0);
}

// ---------------------------------------------------------------------------
// K1: gating. One wave per token, fp64 accumulation -> exactly-rounded logits
// so argmax matches the numpy reference. graw = 1/sum(exp(l-m)).
// ---------------------------------------------------------------------------
__global__ void gate_kernel(const float* __restrict__ x, const float* __restrict__ wg,
                            int* __restrict__ eidx, float* __restrict__ graw) {
    const int wave = threadIdx.x >> 6, lane = threadIdx.x & 63;
    const int tok = blockIdx.x * 4 + wave;
    const float* xr = x + (size_t)tok * MDIM;
    double acc[8] = {0, 0, 0, 0, 0, 0, 0, 0};
#pragma unroll
    for (int kk = 0; kk < 16; ++kk) {
        int i = kk * 64 + lane;
        float xv = xr[i];
        float4 w0 = *(const float4*)(wg + (size_t)i * 8);
        float4 w1v = *(const float4*)(wg + (size_t)i * 8 + 4);
        acc[0] += (double)xv * (double)w0.x;
        acc[1] += (double)xv * (double)w0.y;
        acc[2] += (double)xv * (double)w0.z;
        acc[3] += (double)xv * (double)w0.w;
        acc[4] += (double)xv * (double)w1v.x;
        acc[5] += (double)xv * (double)w1v.y;
        acc[6] += (double)xv * (double)w1v.z;
        acc[7] += (double)xv * (double)w1v.w;
    }
#pragma unroll
    for (int off = 32; off >= 1; off >>= 1) {
#pragma unroll
        for (int e = 0; e < 8; ++e) acc[e] += __shfl_down(acc[e], off);
    }
    if (lane == 0) {
        float l[8];
#pragma unroll
        for (int e = 0; e < 8; ++e) l[e] = (float)acc[e];
        float m = l[0]; int best = 0;
#pragma unroll
        for (int e = 1; e < 8; ++e) { if (l[e] > m) { m = l[e]; best = e; } }
        float den = 0.f;
#pragma unroll
        for (int e = 0; e < 8; ++e) den += expf(l[e] - m);
        eidx[tok] = best;
        graw[tok] = 1.0f / den;
    }
}

// ---------------------------------------------------------------------------
// K2: capacity scan. One block; pos[t] = count of earlier same-expert tokens.
// keep = pos < CAP. slot_token[e*CAP+pos] = t; gfin = gate or 0.
// ---------------------------------------------------------------------------
__global__ void scan_kernel(const int* __restrict__ eidx, const float* __restrict__ graw,
                            float* __restrict__ gfin, int* __restrict__ slot_token) {
    __shared__ int cnt[256][8];
    __shared__ int pfx[256][8];
    const int t = threadIdx.x;
    const int base = t * 32;
    int local[8] = {0, 0, 0, 0, 0, 0, 0, 0};
    for (int j = 0; j < 32; ++j) {
        int ev = eidx[base + j];
#pragma unroll
        for (int e = 0; e < 8; ++e) local[e] += (ev == e);
    }
#pragma unroll
    for (int e = 0; e < 8; ++e) cnt[t][e] = local[e];
    __syncthreads();
    if (t < 8) {
        int run = 0;
        for (int i = 0; i < 256; ++i) { pfx[i][t] = run; run += cnt[i][t]; }
    }
    __syncthreads();
    int run[8];
#pragma unroll
    for (int e = 0; e < 8; ++e) run[e] = pfx[t][e];
    for (int j = 0; j < 32; ++j) {
        int tok = base + j;
        int ev = eidx[tok];
        int pos = 0;
#pragma unroll
        for (int e = 0; e < 8; ++e) { if (ev == e) pos = run[e]; run[e] += (ev == e); }
        if (pos < CAP) {
            gfin[tok] = graw[tok];
            slot_token[ev * CAP + pos] = tok;
        } else {
            gfin[tok] = 0.f;
        }
    }
}

// ---------------------------------------------------------------------------
// K3: dispatch — gather kept token rows into bf16 dispA[E*CAP][MDIM],
// zero-fill unfilled slots.
// ---------------------------------------------------------------------------
__global__ void dispatch_kernel(const float* __restrict__ x, const int* __restrict__ slot_token,
                                short* __restrict__ dispA) {
    const int slot = blockIdx.x;
    const int tok = slot_token[slot];
    const int t = threadIdx.x;
    short4 ov;
    if (tok >= 0) {
        float4 v = *(const float4*)(x + (size_t)tok * MDIM + t * 4);
        ov.x = f2bf(v.x); ov.y = f2bf(v.y); ov.z = f2bf(v.z); ov.w = f2bf(v.w);
    } else {
        ov.x = 0; ov.y = 0; ov.z = 0; ov.w = 0;
    }
    *(short4*)(dispA + (size_t)slot * MDIM + t * 4) = ov;
}

// ---------------------------------------------------------------------------
// K4: fp32 -> bf16 cast + transpose of an [R][C] slab (row stride rstride)
// into [C][R] bf16. 64x64 LDS tiles, coalesced read+write.
// ---------------------------------------------------------------------------
__global__ void cast_transpose_kernel(const float* __restrict__ in, short* __restrict__ out,
                                      int R, int C, int rstride,
                                      size_t in_estride, size_t out_estride) {
    __shared__ float tile[64][65];
    const int e = blockIdx.z;
    const float* src = in + (size_t)e * in_estride;
    short* dst = out + (size_t)e * out_estride;
    const int r0 = blockIdx.x * 64, c0 = blockIdx.y * 64;
    const int t = threadIdx.x;
    const int rr = t >> 4, cq = (t & 15) * 4;
#pragma unroll
    for (int j = 0; j < 4; ++j) {
        int r = rr + j * 16;
        float4 v = *(const float4*)(src + (size_t)(r0 + r) * rstride + c0 + cq);
        tile[r][cq + 0] = v.x; tile[r][cq + 1] = v.y;
        tile[r][cq + 2] = v.z; tile[r][cq + 3] = v.w;
    }
    __syncthreads();
    const int oc = t >> 2, ch = (t & 3) * 16;
    union { short s[16]; int4 v2[2]; } u;
#pragma unroll
    for (int j = 0; j < 16; ++j) u.s[j] = f2bf(tile[ch + j][oc]);
    int4* dp = (int4*)(dst + (size_t)(c0 + oc) * R + r0 + ch);
    dp[0] = u.v2[0]; dp[1] = u.v2[1];
}

// ---------------------------------------------------------------------------
// m97-style GEMM core: C[128x128] tile, A row-major [rows][K] bf16,
// Bt row-major [cols][K] bf16, BK=32, global_load_lds width=16 staging,
// 16x16x32 bf16 MFMA, 4 waves in 2x2, 64x64 quadrant each (4x4 acc).
// Fragment maps (HW-verified m89/m91):
//   A: A[m=lane&15][k=(lane>>4)*8+j];  B: Bt[n=lane&15][k=(lane>>4)*8+j]
//   C/D: col=lane&15, row=(lane>>4)*4+reg
// ---------------------------------------------------------------------------
__device__ __forceinline__ void gemm_tiles(const short* __restrict__ Aexp,
                                           const short* __restrict__ Bexp,
                                           int K, int m0, int n0,
                                           short* ldsA, short* ldsB,
                                           f32x4 acc[4][4]) {
    const int t = threadIdx.x;
    const int wave = t >> 6, lane = t & 63;
    const int lrow = lane >> 2;        // 16 rows per wave-chunk, 4 lanes/row
    const int lk8 = (lane & 3) * 8;    // 8 bf16 = 16B per lane
    const int fr = lane & 15, fq = lane >> 4;
    const int wr = wave >> 1, wc = wave & 1;
    const size_t aBase = (size_t)(m0 + wave * 16 + lrow) * K + lk8;
    const size_t bBase = (size_t)(n0 + wave * 16 + lrow) * K + lk8;

    for (int k0 = 0; k0 < K; k0 += 32) {
#pragma unroll
        for (int j = 0; j < 2; ++j) {
            gld_lds16(Aexp + aBase + (size_t)j * 64 * K + k0,
                      ldsA + (j * 64 + wave * 16) * 32);
            gld_lds16(Bexp + bBase + (size_t)j * 64 * K + k0,
                      ldsB + (j * 64 + wave * 16) * 32);
        }
        __syncthreads();   // drains vmcnt for global_load_lds
        short8v a[4], b[4];
#pragma unroll
        for (int i = 0; i < 4; ++i)
            a[i] = *(const short8v*)(ldsA + (wr * 64 + i * 16 + fr) * 32 + fq * 8);
#pragma unroll
        for (int i = 0; i < 4; ++i)
            b[i] = *(const short8v*)(ldsB + (wc * 64 + i * 16 + fr) * 32 + fq * 8);
#pragma unroll
        for (int i = 0; i < 4; ++i) {
#pragma unroll
            for (int jj = 0; jj < 4; ++jj)
                acc[i][jj] = __builtin_amdgcn_mfma_f32_16x16x32_bf16(a[i], b[jj], acc[i][jj], 0, 0, 0);
        }
        __syncthreads();
    }
}

// GEMM1 half: h[e,c,n] = relu(dispA[e,c,:].w1t[e,n,:] + b1[e,hoff+n]), n in [0,HHALF)
__global__ void gemm1_kernel(const short* __restrict__ dispA, const short* __restrict__ w1t,
                             const float* __restrict__ b1, short* __restrict__ h, int hoff) {
    __shared__ alignas(16) short ldsA[128 * 32];
    __shared__ alignas(16) short ldsB[128 * 32];
    const int e = blockIdx.z;
    const int m0 = blockIdx.x * 128, n0 = blockIdx.y * 128;
    f32x4 acc[4][4];
#pragma unroll
    for (int i = 0; i < 4; ++i)
#pragma unroll
        for (int j = 0; j < 4; ++j) acc[i][j] = (f32x4){0.f, 0.f, 0.f, 0.f};

    gemm_tiles(dispA + (size_t)e * CAP * MDIM, w1t + (size_t)e * HHALF * MDIM,
               MDIM, m0, n0, ldsA, ldsB, acc);

    const int lane = threadIdx.x & 63, wave = threadIdx.x >> 6;
    const int fr = lane & 15, fq = lane >> 4, wr = wave >> 1, wc = wave & 1;
    const float* b1e = b1 + (size_t)e * HDIM + hoff;
    short* hExp = h + (size_t)e * CAP * HHALF;
#pragma unroll
    for (int jj = 0; jj < 4; ++jj) {
        const int gcol = n0 + wc * 64 + jj * 16 + fr;
        const float bias = b1e[gcol];
#pragma unroll
        for (int i = 0; i < 4; ++i) {
#pragma unroll
            for (int r = 0; r < 4; ++r) {
                const int grow = m0 + wr * 64 + i * 16 + fq * 4 + r;
                float v = acc[i][jj][r] + bias;
                v = v > 0.f ? v : 0.f;
                hExp[(size_t)grow * HHALF + gcol] = f2bf(v);
            }
        }
    }
}

// GEMM2 half: eo_part[e,c,m] = h[e,c,:].w2t[e,m,:]; scatter (acc[+b2])*gv into
// out rows. acc_flag==0: out = (acc+b2)*gv ; acc_flag==1: out += acc*gv.
__global__ void gemm2_kernel(const short* __restrict__ h, const short* __restrict__ w2t,
                             const float* __restrict__ b2, const int* __restrict__ slot_token,
                             const float* __restrict__ gfin, float* __restrict__ out,
                             int acc_flag) {
    __shared__ alignas(16) short ldsA[128 * 32];
    __shared__ alignas(16) short ldsB[128 * 32];
    const int e = blockIdx.z;
    const int m0 = blockIdx.x * 128, n0 = blockIdx.y * 128;
    f32x4 acc[4][4];
#pragma unroll
    for (int i = 0; i < 4; ++i)
#pragma unroll
        for (int j = 0; j < 4; ++j) acc[i][j] = (f32x4){0.f, 0.f, 0.f, 0.f};

    gemm_tiles(h + (size_t)e * CAP * HHALF, w2t + (size_t)e * MDIM * HHALF,
               HHALF, m0, n0, ldsA, ldsB, acc);

    const int lane = threadIdx.x & 63, wave = threadIdx.x >> 6;
    const int fr = lane & 15, fq = lane >> 4, wr = wave >> 1, wc = wave & 1;
    const float* b2e = b2 + (size_t)e * MDIM;
#pragma unroll
    for (int i = 0; i < 4; ++i) {
#pragma unroll
        for (int r = 0; r < 4; ++r) {
            const int grow = m0 + wr * 64 + i * 16 + fq * 4 + r;
            const int tok = slot_token[e * CAP + grow];
            if (tok < 0) continue;
            const float gv = gfin[tok];
            float* orow = out + (size_t)tok * MDIM;
            if (acc_flag == 0) {
#pragma unroll
                for (int jj = 0; jj < 4; ++jj) {
                    const int gcol = n0 + wc * 64 + jj * 16 + fr;
                    orow[gcol] = (acc[i][jj][r] + b2e[gcol]) * gv;
                }
            } else {
#pragma unroll
                for (int jj = 0; jj < 4; ++jj) {
                    const int gcol = n0 + wc * 64 + jj * 16 + fr;
                    orow[gcol] += acc[i][jj][r] * gv;
                }
            }
        }
    }
}

// ---------------------------------------------------------------------------
// Workspace layout (bytes) — TOTAL 84,017,152 B (~80.1 MiB):
//   wt    bf16 [E][2048][1024] ping-pong :        0 .. 33,554,432
//   hbuf  bf16 [E][C][HHALF]             : 33,554,432 .. 67,108,864
//   dispA bf16 [E*C][M]                  : 67,108,864 .. 83,886,080
//   eidx/graw/gfin/slot_token            : 83,886,080 .. 84,017,152
// ---------------------------------------------------------------------------
extern "C" void kernel_launch(void* const* d_in, const int* in_sizes, int n_in,
                              void* d_out, int out_size, void* d_ws, size_t ws_size,
                              hipStream_t stream) {
    const float* x  = (const float*)d_in[0];
    const float* wg = (const float*)d_in[1];
    const float* w1 = (const float*)d_in[2];
    const float* b1 = (const float*)d_in[3];
    const float* w2 = (const float*)d_in[4];
    const float* b2 = (const float*)d_in[5];
    float* out = (float*)d_out;

    char* ws = (char*)d_ws;
    short* wt    = (short*)(ws);
    short* hbuf  = (short*)(ws + 33554432);
    short* dispA = (short*)(ws + 67108864);
    int*   eidx  = (int*)  (ws + 83886080);
    float* graw  = (float*)(ws + 83886080 + 32768);
    float* gfin  = (float*)(ws + 83886080 + 65536);
    int*   slot_token = (int*)(ws + 83886080 + 98304);

    hipMemsetAsync(slot_token, 0xFF, S_TOK * sizeof(int), stream);       // -1
    hipMemsetAsync(d_out, 0, (size_t)out_size * sizeof(float), stream);  // dropped tokens -> 0

    gate_kernel<<<S_TOK / 4, 256, 0, stream>>>(x, wg, eidx, graw);
    scan_kernel<<<1, 256, 0, stream>>>(eidx, graw, gfin, slot_token);
    dispatch_kernel<<<EEXP * CAP, 256, 0, stream>>>(x, slot_token, dispA);

    for (int half = 0; half < 2; ++half) {
        // w1 slab: in [E][M][H], rows r=M (stride H), cols c = hoff..hoff+2048
        cast_transpose_kernel<<<dim3(MDIM / 64, HHALF / 64, EEXP), 256, 0, stream>>>(
            w1 + (size_t)half * HHALF, wt, MDIM, HHALF, HDIM,
            (size_t)MDIM * HDIM, (size_t)HHALF * MDIM);
        gemm1_kernel<<<dim3(CAP / 128, HHALF / 128, EEXP), 256, 0, stream>>>(
            dispA, wt, b1, hbuf, half * HHALF);
        // w2 slab: in [E][H][M], rows r = hoff..hoff+2048 (stride M), cols c=M
        cast_transpose_kernel<<<dim3(HHALF / 64, MDIM / 64, EEXP), 256, 0, stream>>>(
            w2 + (size_t)half * HHALF * MDIM, wt, HHALF, MDIM, MDIM,
            (size_t)HDIM * MDIM, (size_t)MDIM * HHALF);
        gemm2_kernel<<<dim3(CAP / 128, MDIM / 128, EEXP), 256, 0, stream>>>(
            hbuf, wt, b2, slot_token, gfin, out, half);
    }
}

// Round 3
// 602.684 us; speedup vs baseline: 1.0001x; 1.0001x over previous
//
#include <hip/hip_runtime.h>
#include <cstdint>
#include <cstddef>

// Problem shape (fixed): B=4, Sq=2048 -> S=8192 tokens, M=1024, E=8, H=4096,
// C=S/E=1024 capacity.
// WS BUDGET: keep total workspace <= ~84 MB (r1 failed post-timing with a
// 218 MB footprint -> suspected d_ws overrun corrupting pristine inputs;
// r2's 84 MB layout passes. Do not grow past this without evidence.)
// R3 change: GEMM K-loop BK=32 -> BK=64 via two stacked BK=32 LDS panels
// (32 KB LDS/block, occupancy unchanged at ~3 blocks/CU) -> half the
// __syncthreads/vmcnt-drain pairs, 32 MFMA per barrier instead of 16.
#define S_TOK 8192
#define MDIM  1024
#define EEXP  8
#define HDIM  4096
#define HHALF 2048
#define CAP   1024

typedef __attribute__((ext_vector_type(8))) short short8v;   // 8 bf16 in 4 VGPRs
typedef __attribute__((ext_vector_type(4))) float f32x4;

__device__ __forceinline__ short f2bf(float f) {
    __bf16 b = (__bf16)f;                 // RNE hardware convert on gfx950
    return __builtin_bit_cast(short, b);
}

__device__ __forceinline__ void gld_lds16(const void* g, void* l) {
    __builtin_amdgcn_global_load_lds(
        (const __attribute__((address_space(1))) void*)g,
        (__attribute__((address_space(3))) void*)l, 16, 0, 0);
}

// ---------------------------------------------------------------------------
// K1: gating. One wave per token, fp64 accumulation -> exactly-rounded logits
// so argmax matches the numpy reference. graw = 1/sum(exp(l-m)).
// ---------------------------------------------------------------------------
__global__ void gate_kernel(const float* __restrict__ x, const float* __restrict__ wg,
                            int* __restrict__ eidx, float* __restrict__ graw) {
    const int wave = threadIdx.x >> 6, lane = threadIdx.x & 63;
    const int tok = blockIdx.x * 4 + wave;
    const float* xr = x + (size_t)tok * MDIM;
    double acc[8] = {0, 0, 0, 0, 0, 0, 0, 0};
#pragma unroll
    for (int kk = 0; kk < 16; ++kk) {
        int i = kk * 64 + lane;
        float xv = xr[i];
        float4 w0 = *(const float4*)(wg + (size_t)i * 8);
        float4 w1v = *(const float4*)(wg + (size_t)i * 8 + 4);
        acc[0] += (double)xv * (double)w0.x;
        acc[1] += (double)xv * (double)w0.y;
        acc[2] += (double)xv * (double)w0.z;
        acc[3] += (double)xv * (double)w0.w;
        acc[4] += (double)xv * (double)w1v.x;
        acc[5] += (double)xv * (double)w1v.y;
        acc[6] += (double)xv * (double)w1v.z;
        acc[7] += (double)xv * (double)w1v.w;
    }
#pragma unroll
    for (int off = 32; off >= 1; off >>= 1) {
#pragma unroll
        for (int e = 0; e < 8; ++e) acc[e] += __shfl_down(acc[e], off);
    }
    if (lane == 0) {
        float l[8];
#pragma unroll
        for (int e = 0; e < 8; ++e) l[e] = (float)acc[e];
        float m = l[0]; int best = 0;
#pragma unroll
        for (int e = 1; e < 8; ++e) { if (l[e] > m) { m = l[e]; best = e; } }
        float den = 0.f;
#pragma unroll
        for (int e = 0; e < 8; ++e) den += expf(l[e] - m);
        eidx[tok] = best;
        graw[tok] = 1.0f / den;
    }
}

// ---------------------------------------------------------------------------
// K2: capacity scan. One block; pos[t] = count of earlier same-expert tokens.
// keep = pos < CAP. slot_token[e*CAP+pos] = t; gfin = gate or 0.
// ---------------------------------------------------------------------------
__global__ void scan_kernel(const int* __restrict__ eidx, const float* __restrict__ graw,
                            float* __restrict__ gfin, int* __restrict__ slot_token) {
    __shared__ int cnt[256][8];
    __shared__ int pfx[256][8];
    const int t = threadIdx.x;
    const int base = t * 32;
    int local[8] = {0, 0, 0, 0, 0, 0, 0, 0};
    for (int j = 0; j < 32; ++j) {
        int ev = eidx[base + j];
#pragma unroll
        for (int e = 0; e < 8; ++e) local[e] += (ev == e);
    }
#pragma unroll
    for (int e = 0; e < 8; ++e) cnt[t][e] = local[e];
    __syncthreads();
    if (t < 8) {
        int run = 0;
        for (int i = 0; i < 256; ++i) { pfx[i][t] = run; run += cnt[i][t]; }
    }
    __syncthreads();
    int run[8];
#pragma unroll
    for (int e = 0; e < 8; ++e) run[e] = pfx[t][e];
    for (int j = 0; j < 32; ++j) {
        int tok = base + j;
        int ev = eidx[tok];
        int pos = 0;
#pragma unroll
        for (int e = 0; e < 8; ++e) { if (ev == e) pos = run[e]; run[e] += (ev == e); }
        if (pos < CAP) {
            gfin[tok] = graw[tok];
            slot_token[ev * CAP + pos] = tok;
        } else {
            gfin[tok] = 0.f;
        }
    }
}

// ---------------------------------------------------------------------------
// K3: dispatch — gather kept token rows into bf16 dispA[E*CAP][MDIM],
// zero-fill unfilled slots.
// ---------------------------------------------------------------------------
__global__ void dispatch_kernel(const float* __restrict__ x, const int* __restrict__ slot_token,
                                short* __restrict__ dispA) {
    const int slot = blockIdx.x;
    const int tok = slot_token[slot];
    const int t = threadIdx.x;
    short4 ov;
    if (tok >= 0) {
        float4 v = *(const float4*)(x + (size_t)tok * MDIM + t * 4);
        ov.x = f2bf(v.x); ov.y = f2bf(v.y); ov.z = f2bf(v.z); ov.w = f2bf(v.w);
    } else {
        ov.x = 0; ov.y = 0; ov.z = 0; ov.w = 0;
    }
    *(short4*)(dispA + (size_t)slot * MDIM + t * 4) = ov;
}

// ---------------------------------------------------------------------------
// K4: fp32 -> bf16 cast + transpose of an [R][C] slab (row stride rstride)
// into [C][R] bf16. 64x64 LDS tiles, coalesced read+write.
// ---------------------------------------------------------------------------
__global__ void cast_transpose_kernel(const float* __restrict__ in, short* __restrict__ out,
                                      int R, int C, int rstride,
                                      size_t in_estride, size_t out_estride) {
    __shared__ float tile[64][65];
    const int e = blockIdx.z;
    const float* src = in + (size_t)e * in_estride;
    short* dst = out + (size_t)e * out_estride;
    const int r0 = blockIdx.x * 64, c0 = blockIdx.y * 64;
    const int t = threadIdx.x;
    const int rr = t >> 4, cq = (t & 15) * 4;
#pragma unroll
    for (int j = 0; j < 4; ++j) {
        int r = rr + j * 16;
        float4 v = *(const float4*)(src + (size_t)(r0 + r) * rstride + c0 + cq);
        tile[r][cq + 0] = v.x; tile[r][cq + 1] = v.y;
        tile[r][cq + 2] = v.z; tile[r][cq + 3] = v.w;
    }
    __syncthreads();
    const int oc = t >> 2, ch = (t & 3) * 16;
    union { short s[16]; int4 v2[2]; } u;
#pragma unroll
    for (int j = 0; j < 16; ++j) u.s[j] = f2bf(tile[ch + j][oc]);
    int4* dp = (int4*)(dst + (size_t)(c0 + oc) * R + r0 + ch);
    dp[0] = u.v2[0]; dp[1] = u.v2[1];
}

// ---------------------------------------------------------------------------
// GEMM core, BK=64 double-panel variant of the m97 structure.
// C[128x128] tile, A row-major [rows][K] bf16, Bt row-major [cols][K] bf16.
// Per outer iter (K advance 64): stage TWO BK=32 panels (each the verified
// r2 layout: [128 rows][32 k] contiguous), ONE barrier, consume both panels
// (2 x 16 MFMA), barrier. Fragments loaded per panel sequentially so VGPR
// use matches r2 (~164) -> occupancy unchanged; LDS = 32 KB/block.
// Fragment maps (HW-verified m89/m91):
//   A: A[m=lane&15][k=(lane>>4)*8+j];  B: Bt[n=lane&15][k=(lane>>4)*8+j]
//   C/D: col=lane&15, row=(lane>>4)*4+reg
// ---------------------------------------------------------------------------
__device__ __forceinline__ void gemm_tiles(const short* __restrict__ Aexp,
                                           const short* __restrict__ Bexp,
                                           int K, int m0, int n0,
                                           short* ldsA, short* ldsB,
                                           f32x4 acc[4][4]) {
    const int t = threadIdx.x;
    const int wave = t >> 6, lane = t & 63;
    const int lrow = lane >> 2;        // 16 rows per wave-chunk, 4 lanes/row
    const int lk8 = (lane & 3) * 8;    // 8 bf16 = 16B per lane
    const int fr = lane & 15, fq = lane >> 4;
    const int wr = wave >> 1, wc = wave & 1;
    const size_t aBase = (size_t)(m0 + wave * 16 + lrow) * K + lk8;
    const size_t bBase = (size_t)(n0 + wave * 16 + lrow) * K + lk8;

    for (int k0 = 0; k0 < K; k0 += 64) {
        // stage two BK=32 panels: panel p at LDS offset p*128*32
#pragma unroll
        for (int p = 0; p < 2; ++p) {
#pragma unroll
            for (int j = 0; j < 2; ++j) {
                gld_lds16(Aexp + aBase + (size_t)j * 64 * K + k0 + p * 32,
                          ldsA + p * 128 * 32 + (j * 64 + wave * 16) * 32);
                gld_lds16(Bexp + bBase + (size_t)j * 64 * K + k0 + p * 32,
                          ldsB + p * 128 * 32 + (j * 64 + wave * 16) * 32);
            }
        }
        __syncthreads();   // drains vmcnt for global_load_lds
#pragma unroll
        for (int p = 0; p < 2; ++p) {
            const short* pA = ldsA + p * 128 * 32;
            const short* pB = ldsB + p * 128 * 32;
            short8v a[4], b[4];
#pragma unroll
            for (int i = 0; i < 4; ++i)
                a[i] = *(const short8v*)(pA + (wr * 64 + i * 16 + fr) * 32 + fq * 8);
#pragma unroll
            for (int i = 0; i < 4; ++i)
                b[i] = *(const short8v*)(pB + (wc * 64 + i * 16 + fr) * 32 + fq * 8);
#pragma unroll
            for (int i = 0; i < 4; ++i) {
#pragma unroll
                for (int jj = 0; jj < 4; ++jj)
                    acc[i][jj] = __builtin_amdgcn_mfma_f32_16x16x32_bf16(a[i], b[jj], acc[i][jj], 0, 0, 0);
            }
        }
        __syncthreads();
    }
}

// GEMM1 half: h[e,c,n] = relu(dispA[e,c,:].w1t[e,n,:] + b1[e,hoff+n]), n in [0,HHALF)
__global__ void gemm1_kernel(const short* __restrict__ dispA, const short* __restrict__ w1t,
                             const float* __restrict__ b1, short* __restrict__ h, int hoff) {
    __shared__ alignas(16) short ldsA[2 * 128 * 32];
    __shared__ alignas(16) short ldsB[2 * 128 * 32];
    const int e = blockIdx.z;
    const int m0 = blockIdx.x * 128, n0 = blockIdx.y * 128;
    f32x4 acc[4][4];
#pragma unroll
    for (int i = 0; i < 4; ++i)
#pragma unroll
        for (int j = 0; j < 4; ++j) acc[i][j] = (f32x4){0.f, 0.f, 0.f, 0.f};

    gemm_tiles(dispA + (size_t)e * CAP * MDIM, w1t + (size_t)e * HHALF * MDIM,
               MDIM, m0, n0, ldsA, ldsB, acc);

    const int lane = threadIdx.x & 63, wave = threadIdx.x >> 6;
    const int fr = lane & 15, fq = lane >> 4, wr = wave >> 1, wc = wave & 1;
    const float* b1e = b1 + (size_t)e * HDIM + hoff;
    short* hExp = h + (size_t)e * CAP * HHALF;
#pragma unroll
    for (int jj = 0; jj < 4; ++jj) {
        const int gcol = n0 + wc * 64 + jj * 16 + fr;
        const float bias = b1e[gcol];
#pragma unroll
        for (int i = 0; i < 4; ++i) {
#pragma unroll
            for (int r = 0; r < 4; ++r) {
                const int grow = m0 + wr * 64 + i * 16 + fq * 4 + r;
                float v = acc[i][jj][r] + bias;
                v = v > 0.f ? v : 0.f;
                hExp[(size_t)grow * HHALF + gcol] = f2bf(v);
            }
        }
    }
}

// GEMM2 half: eo_part[e,c,m] = h[e,c,:].w2t[e,m,:]; scatter (acc[+b2])*gv into
// out rows. acc_flag==0: out = (acc+b2)*gv ; acc_flag==1: out += acc*gv.
__global__ void gemm2_kernel(const short* __restrict__ h, const short* __restrict__ w2t,
                             const float* __restrict__ b2, const int* __restrict__ slot_token,
                             const float* __restrict__ gfin, float* __restrict__ out,
                             int acc_flag) {
    __shared__ alignas(16) short ldsA[2 * 128 * 32];
    __shared__ alignas(16) short ldsB[2 * 128 * 32];
    const int e = blockIdx.z;
    const int m0 = blockIdx.x * 128, n0 = blockIdx.y * 128;
    f32x4 acc[4][4];
#pragma unroll
    for (int i = 0; i < 4; ++i)
#pragma unroll
        for (int j = 0; j < 4; ++j) acc[i][j] = (f32x4){0.f, 0.f, 0.f, 0.f};

    gemm_tiles(h + (size_t)e * CAP * HHALF, w2t + (size_t)e * MDIM * HHALF,
               HHALF, m0, n0, ldsA, ldsB, acc);

    const int lane = threadIdx.x & 63, wave = threadIdx.x >> 6;
    const int fr = lane & 15, fq = lane >> 4, wr = wave >> 1, wc = wave & 1;
    const float* b2e = b2 + (size_t)e * MDIM;
#pragma unroll
    for (int i = 0; i < 4; ++i) {
#pragma unroll
        for (int r = 0; r < 4; ++r) {
            const int grow = m0 + wr * 64 + i * 16 + fq * 4 + r;
            const int tok = slot_token[e * CAP + grow];
            if (tok < 0) continue;
            const float gv = gfin[tok];
            float* orow = out + (size_t)tok * MDIM;
            if (acc_flag == 0) {
#pragma unroll
                for (int jj = 0; jj < 4; ++jj) {
                    const int gcol = n0 + wc * 64 + jj * 16 + fr;
                    orow[gcol] = (acc[i][jj][r] + b2e[gcol]) * gv;
                }
            } else {
#pragma unroll
                for (int jj = 0; jj < 4; ++jj) {
                    const int gcol = n0 + wc * 64 + jj * 16 + fr;
                    orow[gcol] += acc[i][jj][r] * gv;
                }
            }
        }
    }
}

// ---------------------------------------------------------------------------
// Workspace layout (bytes) — TOTAL 84,017,152 B (~80.1 MiB):
//   wt    bf16 [E][2048][1024] ping-pong :        0 .. 33,554,432
//   hbuf  bf16 [E][C][HHALF]             : 33,554,432 .. 67,108,864
//   dispA bf16 [E*C][M]                  : 67,108,864 .. 83,886,080
//   eidx/graw/gfin/slot_token            : 83,886,080 .. 84,017,152
// ---------------------------------------------------------------------------
extern "C" void kernel_launch(void* const* d_in, const int* in_sizes, int n_in,
                              void* d_out, int out_size, void* d_ws, size_t ws_size,
                              hipStream_t stream) {
    const float* x  = (const float*)d_in[0];
    const float* wg = (const float*)d_in[1];
    const float* w1 = (const float*)d_in[2];
    const float* b1 = (const float*)d_in[3];
    const float* w2 = (const float*)d_in[4];
    const float* b2 = (const float*)d_in[5];
    float* out = (float*)d_out;

    char* ws = (char*)d_ws;
    short* wt    = (short*)(ws);
    short* hbuf  = (short*)(ws + 33554432);
    short* dispA = (short*)(ws + 67108864);
    int*   eidx  = (int*)  (ws + 83886080);
    float* graw  = (float*)(ws + 83886080 + 32768);
    float* gfin  = (float*)(ws + 83886080 + 65536);
    int*   slot_token = (int*)(ws + 83886080 + 98304);

    hipMemsetAsync(slot_token, 0xFF, S_TOK * sizeof(int), stream);       // -1
    hipMemsetAsync(d_out, 0, (size_t)out_size * sizeof(float), stream);  // dropped tokens -> 0

    gate_kernel<<<S_TOK / 4, 256, 0, stream>>>(x, wg, eidx, graw);
    scan_kernel<<<1, 256, 0, stream>>>(eidx, graw, gfin, slot_token);
    dispatch_kernel<<<EEXP * CAP, 256, 0, stream>>>(x, slot_token, dispA);

    for (int half = 0; half < 2; ++half) {
        // w1 slab: in [E][M][H], rows r=M (stride H), cols c = hoff..hoff+2048
        cast_transpose_kernel<<<dim3(MDIM / 64, HHALF / 64, EEXP), 256, 0, stream>>>(
            w1 + (size_t)half * HHALF, wt, MDIM, HHALF, HDIM,
            (size_t)MDIM * HDIM, (size_t)HHALF * MDIM);
        gemm1_kernel<<<dim3(CAP / 128, HHALF / 128, EEXP), 256, 0, stream>>>(
            dispA, wt, b1, hbuf, half * HHALF);
        // w2 slab: in [E][H][M], rows r = hoff..hoff+2048 (stride M), cols c=M
        cast_transpose_kernel<<<dim3(HHALF / 64, MDIM / 64, EEXP), 256, 0, stream>>>(
            w2 + (size_t)half * HHALF * MDIM, wt, HHALF, MDIM, MDIM,
            (size_t)HDIM * MDIM, (size_t)MDIM * HHALF);
        gemm2_kernel<<<dim3(CAP / 128, MDIM / 128, EEXP), 256, 0, stream>>>(
            hbuf, wt, b2, slot_token, gfin, out, half);
    }
}